// Round 1
// baseline (341.357 us; speedup 1.0000x reference)
//
#include <hip/hip_runtime.h>
#include <hip/hip_bf16.h>

#define K_DIM 4096
#define N_DIM 4096
#define M_DIM 4096

#define BM 128
#define BN 128
#define BK 32

typedef __attribute__((ext_vector_type(8))) short bf16x8;   // 8 bf16 in 4 VGPRs
typedef __attribute__((ext_vector_type(4))) float f32x4;
typedef __attribute__((ext_vector_type(8))) unsigned short u16x8;

// ---------- fp32 -> bf16 (round-to-nearest-even) ----------
__device__ __forceinline__ unsigned short f2bf(float f) {
    union { float f; unsigned int u; } v; v.f = f;
    unsigned int u = v.u;
    return (unsigned short)((u + 0x7fffu + ((u >> 16) & 1u)) >> 16);
}

__global__ void cvt_f32_to_bf16(const float* __restrict__ src,
                                unsigned short* __restrict__ dst, int n) {
    int i = (blockIdx.x * blockDim.x + threadIdx.x) * 8;
    if (i >= n) return;
    float4 f0 = *(const float4*)(src + i);
    float4 f1 = *(const float4*)(src + i + 4);
    u16x8 o;
    o[0] = f2bf(f0.x); o[1] = f2bf(f0.y); o[2] = f2bf(f0.z); o[3] = f2bf(f0.w);
    o[4] = f2bf(f1.x); o[5] = f2bf(f1.y); o[6] = f2bf(f1.z); o[7] = f2bf(f1.w);
    *(u16x8*)(dst + i) = o;
}

// ---------- async global->LDS, 16B per lane ----------
__device__ __forceinline__ void gl_lds16(const void* g, void* l) {
    __builtin_amdgcn_global_load_lds(
        (const __attribute__((address_space(1))) void*)g,
        (__attribute__((address_space(3))) void*)l,
        16, 0, 0);
}

// ---------- GEMM: C[M,N] = A[M,K] * B[N,K]^T + bias[N] ----------
// BF16SRC=true: A,B are pre-converted bf16 (use global_load_lds).
// BF16SRC=false: A,B are fp32; convert inline while staging to LDS.
template <bool BF16SRC>
__global__ __launch_bounds__(256) void gemm_bt(
    const void* __restrict__ Aptr, const void* __restrict__ Bptr,
    const float* __restrict__ bias, float* __restrict__ C) {

    __shared__ __align__(16) unsigned short As[BM * BK];  // 8 KB, K-contig rows
    __shared__ __align__(16) unsigned short Bs[BN * BK];  // 8 KB

    const int tid  = threadIdx.x;
    const int wave = tid >> 6;
    const int lane = tid & 63;
    const int l16  = lane & 15;
    const int quad = lane >> 4;

    const int bm = blockIdx.y * BM;
    const int bn = blockIdx.x * BN;

    const int wm = (wave & 1) * 64;   // wave row offset in block tile
    const int wn = (wave >> 1) * 64;  // wave col offset

    f32x4 acc[4][4] = {};

    for (int k0 = 0; k0 < K_DIM; k0 += BK) {
        __syncthreads();  // previous compute done before overwriting LDS

        if constexpr (BF16SRC) {
            const unsigned short* A = (const unsigned short*)Aptr;
            const unsigned short* B = (const unsigned short*)Bptr;
            // chunk c = tid covers LDS bytes [c*16, c*16+16) = row c>>2, k (c&3)*8
            const int row = tid >> 2;
            const int kc  = (tid & 3) << 3;
            gl_lds16(&A[(size_t)(bm + row) * K_DIM + k0 + kc],      &As[wave * 512]);
            gl_lds16(&A[(size_t)(bm + 64 + row) * K_DIM + k0 + kc], &As[2048 + wave * 512]);
            gl_lds16(&B[(size_t)(bn + row) * K_DIM + k0 + kc],      &Bs[wave * 512]);
            gl_lds16(&B[(size_t)(bn + 64 + row) * K_DIM + k0 + kc], &Bs[2048 + wave * 512]);
        } else {
            const float* A = (const float*)Aptr;
            const float* B = (const float*)Bptr;
            // each thread: 16 elems = half an LDS row
            const int row = tid >> 1;
            const int kc  = (tid & 1) << 4;
            {
                const float* s = &A[(size_t)(bm + row) * K_DIM + k0 + kc];
                u16x8 o0, o1;
                float4 f0 = *(const float4*)(s + 0);
                float4 f1 = *(const float4*)(s + 4);
                float4 f2 = *(const float4*)(s + 8);
                float4 f3 = *(const float4*)(s + 12);
                o0[0]=f2bf(f0.x); o0[1]=f2bf(f0.y); o0[2]=f2bf(f0.z); o0[3]=f2bf(f0.w);
                o0[4]=f2bf(f1.x); o0[5]=f2bf(f1.y); o0[6]=f2bf(f1.z); o0[7]=f2bf(f1.w);
                o1[0]=f2bf(f2.x); o1[1]=f2bf(f2.y); o1[2]=f2bf(f2.z); o1[3]=f2bf(f2.w);
                o1[4]=f2bf(f3.x); o1[5]=f2bf(f3.y); o1[6]=f2bf(f3.z); o1[7]=f2bf(f3.w);
                *(u16x8*)&As[row * BK + kc]     = o0;
                *(u16x8*)&As[row * BK + kc + 8] = o1;
            }
            {
                const float* s = &B[(size_t)(bn + row) * K_DIM + k0 + kc];
                u16x8 o0, o1;
                float4 f0 = *(const float4*)(s + 0);
                float4 f1 = *(const float4*)(s + 4);
                float4 f2 = *(const float4*)(s + 8);
                float4 f3 = *(const float4*)(s + 12);
                o0[0]=f2bf(f0.x); o0[1]=f2bf(f0.y); o0[2]=f2bf(f0.z); o0[3]=f2bf(f0.w);
                o0[4]=f2bf(f1.x); o0[5]=f2bf(f1.y); o0[6]=f2bf(f1.z); o0[7]=f2bf(f1.w);
                o1[0]=f2bf(f2.x); o1[1]=f2bf(f2.y); o1[2]=f2bf(f2.z); o1[3]=f2bf(f2.w);
                o1[4]=f2bf(f3.x); o1[5]=f2bf(f3.y); o1[6]=f2bf(f3.z); o1[7]=f2bf(f3.w);
                *(u16x8*)&Bs[row * BK + kc]     = o0;
                *(u16x8*)&Bs[row * BK + kc + 8] = o1;
            }
        }

        __syncthreads();  // staging visible (emits vmcnt(0)+lgkmcnt(0) drain)

        // A-frag: lane holds A[m=l16][k=quad*8+j]; B-frag: B[k=quad*8+j][n=l16]
        bf16x8 af[4], bfv[4];
#pragma unroll
        for (int t = 0; t < 4; t++)
            af[t] = *(const bf16x8*)&As[(wm + t * 16 + l16) * BK + quad * 8];
#pragma unroll
        for (int t = 0; t < 4; t++)
            bfv[t] = *(const bf16x8*)&Bs[(wn + t * 16 + l16) * BK + quad * 8];
#pragma unroll
        for (int i = 0; i < 4; i++)
#pragma unroll
            for (int j = 0; j < 4; j++)
                acc[i][j] = __builtin_amdgcn_mfma_f32_16x16x32_bf16(
                    af[i], bfv[j], acc[i][j], 0, 0, 0);
    }

    // epilogue: D[row=quad*4+r][col=l16] per 16x16 tile; add bias
#pragma unroll
    for (int i = 0; i < 4; i++) {
        const int rbase = bm + wm + i * 16 + quad * 4;
#pragma unroll
        for (int j = 0; j < 4; j++) {
            const int col = bn + wn + j * 16 + l16;
            const float bv = bias[col];
#pragma unroll
            for (int r = 0; r < 4; r++)
                C[(size_t)(rbase + r) * N_DIM + col] = acc[i][j][r] + bv;
        }
    }
}

extern "C" void kernel_launch(void* const* d_in, const int* in_sizes, int n_in,
                              void* d_out, int out_size, void* d_ws, size_t ws_size,
                              hipStream_t stream) {
    const float* x = (const float*)d_in[0];   // [M, K]
    const float* W = (const float*)d_in[1];   // [N, K]
    const float* b = (const float*)d_in[2];   // [N]
    float* out = (float*)d_out;               // [M, N]

    const size_t elems = (size_t)M_DIM * K_DIM;  // == N*K here
    const size_t need  = 2 * elems * sizeof(unsigned short);  // 64 MB

    dim3 grid(N_DIM / BN, M_DIM / BM);
    dim3 block(256);

    if (ws_size >= need) {
        unsigned short* xb = (unsigned short*)d_ws;
        unsigned short* wb = xb + elems;
        const int n = (int)elems;
        const int cblocks = n / (256 * 8);
        cvt_f32_to_bf16<<<cblocks, 256, 0, stream>>>(x, xb, n);
        cvt_f32_to_bf16<<<cblocks, 256, 0, stream>>>(W, wb, n);
        gemm_bt<true><<<grid, block, 0, stream>>>(xb, wb, b, out);
    } else {
        gemm_bt<false><<<grid, block, 0, stream>>>(x, W, b, out);
    }
}